// Round 12
// baseline (565.324 us; speedup 1.0000x reference)
//
#include <hip/hip_runtime.h>

// Problem constants (match reference)
#define BATCH 4
#define SLEN  4096
#define DIMK  4096
#define HD    512
#define RD    64
#define NCOLS 2048          // [kv(1024) | sc(1024)]
#define MROWS (BATCH*SLEN)  // 16384

typedef __attribute__((ext_vector_type(8))) short bf16x8;
typedef __attribute__((ext_vector_type(4))) float f32x4;
typedef unsigned short u16;

// ---------- bf16 helpers ----------
__device__ inline u16 f2b(float f) {
  union { float f; unsigned u; } x; x.f = f;
  unsigned r = (x.u + 0x7fffu + ((x.u >> 16) & 1u)) >> 16;
  return (u16)r;
}
__device__ inline float b2f(u16 u) {
  union { float f; unsigned u; } x; x.u = ((unsigned)u) << 16; return x.f;
}

#define GLL16(gp, lp) __builtin_amdgcn_global_load_lds( \
    (__attribute__((address_space(1))) void*)(gp),      \
    (__attribute__((address_space(3))) void*)(lp), 16, 0, 0)

// ---------- kernel 1: x (f32) -> bf16 ----------
__global__ __launch_bounds__(256) void cvt_x_kernel(const float4* __restrict__ x,
                                                    u16* __restrict__ xb) {
  size_t i = (size_t)blockIdx.x * 256 + threadIdx.x;
  float4 a = x[2 * i], b = x[2 * i + 1];
  bf16x8 v;
  v[0] = (short)f2b(a.x); v[1] = (short)f2b(a.y);
  v[2] = (short)f2b(a.z); v[3] = (short)f2b(a.w);
  v[4] = (short)f2b(b.x); v[5] = (short)f2b(b.y);
  v[6] = (short)f2b(b.z); v[7] = (short)f2b(b.w);
  *(bf16x8*)(xb + i * 8) = v;
}

// ---------- kernel 2: Wt[n][k] = [wkv|wgate][k][n] as bf16 ----------
__global__ __launch_bounds__(256) void build_wt_kernel(const float* __restrict__ wkv,
                                                       const float* __restrict__ wg,
                                                       u16* __restrict__ Wt) {
  __shared__ u16 tile[64][72];
  const int n0 = blockIdx.x * 64;
  const int k0 = blockIdx.y * 64;
  const float* src = (n0 < 1024) ? wkv : wg;
  const int nbase = (n0 < 1024) ? n0 : (n0 - 1024);
  const int t = threadIdx.x;
  const int nn = t & 63, kq = t >> 6;
  #pragma unroll
  for (int j = 0; j < 16; ++j) {
    int k = kq + j * 4;
    float v = src[(size_t)(k0 + k) * 1024 + nbase + nn];
    tile[nn][k] = f2b(v);
  }
  __syncthreads();
  const int kk8 = (t & 7) * 8;
  #pragma unroll
  for (int j = 0; j < 2; ++j) {
    int nn2 = (t >> 3) + j * 32;
    bf16x8 v = *(bf16x8*)&tile[nn2][kk8];
    *(bf16x8*)&Wt[(size_t)(n0 + nn2) * DIMK + k0 + kk8] = v;
  }
}

// ---------- kernel 3: GEMM — m97 structure, BK=64 (barrier-amortized) ----------
// R11 (BK=32) confirmed the m97 model: 727 TF, overhead ~370 cyc/K-step paid
// 128x. BK=64 halves the barrier/drain count per FLOP: two 8 KiB sub-tiles per
// operand staged per step (8 GLL), computed as two sequential k-halves.
// 32 KiB LDS -> still 4 blocks/CU. Staging map + swizzle + banding unchanged.
__global__ __launch_bounds__(256, 4) void gemm_kernel(const u16* __restrict__ A,
                                                      const u16* __restrict__ Bt,
                                                      u16* __restrict__ C) {
  __shared__ __align__(16) u16 Asm[2][128][32];     // 16 KiB
  __shared__ __align__(16) u16 Bsm[2][128][32];     // 16 KiB
  const int t = threadIdx.x;
  const int lane = t & 63, wave = t >> 6;

  // XCD column-banding: nwg=2048; XCD x (= orig&7, round-robin m09) gets
  // lids [x*256,(x+1)*256) = nt in {2x,2x+1}, all 128 mt.
  const int orig = blockIdx.x;
  const int lid = (orig & 7) * 256 + (orig >> 3);
  const int nt = lid >> 7, mt = lid & 127;
  const int m0 = mt * 128, n0 = nt * 128;
  const int wr = wave >> 1, wc = wave & 1;          // 2x2 waves of 64x64

  f32x4 acc[4][4] = {};

  // staging map: thread t -> rowT = t>>2 (0..63), granule colT = t&3 (16B).
  // LDS linear offset = t*16 per GLL. global granule pre-swizzled:
  // colX = colT ^ X(rowT), X(r) = (r&3)^((r>>2)&3); X(r+64) = X(r).
  const int rowT = t >> 2, colT = t & 3;
  const int colX = colT ^ (rowT & 3) ^ ((rowT >> 2) & 3);
  const u16* gA0 = A  + (size_t)(m0 + rowT) * DIMK + colX * 8;
  const u16* gB0 = Bt + (size_t)(n0 + rowT) * DIMK + colX * 8;
  const u16* gA1 = A  + (size_t)(m0 + 64 + rowT) * DIMK + colX * 8;
  const u16* gB1 = Bt + (size_t)(n0 + 64 + rowT) * DIMK + colX * 8;
  u16* lA0[2] = { &Asm[0][rowT][colT * 8], &Asm[1][rowT][colT * 8] };
  u16* lA1[2] = { &Asm[0][64 + rowT][colT * 8], &Asm[1][64 + rowT][colT * 8] };
  u16* lB0[2] = { &Bsm[0][rowT][colT * 8], &Bsm[1][rowT][colT * 8] };
  u16* lB1[2] = { &Bsm[0][64 + rowT][colT * 8], &Bsm[1][64 + rowT][colT * 8] };

  // fragment read addressing (swizzled k-granule; X depends only on fr)
  const int fr = lane & 15, fk = lane >> 4;
  const int fkx = (fk ^ (fr & 3) ^ ((fr >> 2) & 3)) * 8;

  for (int kk = 0; kk < DIMK; kk += 64) {
    __syncthreads();                 // previous step's LDS reads complete
    #pragma unroll
    for (int h = 0; h < 2; ++h) {
      GLL16(gA0 + kk + h * 32, lA0[h]);
      GLL16(gA1 + kk + h * 32, lA1[h]);
      GLL16(gB0 + kk + h * 32, lB0[h]);
      GLL16(gB1 + kk + h * 32, lB1[h]);
    }
    __syncthreads();                 // loads landed (compiler drains vmcnt)

    #pragma unroll
    for (int h = 0; h < 2; ++h) {
      bf16x8 af[4], bf[4];
      #pragma unroll
      for (int m = 0; m < 4; ++m)
        af[m] = *(const bf16x8*)&Asm[h][wr * 64 + m * 16 + fr][fkx];
      #pragma unroll
      for (int n = 0; n < 4; ++n)
        bf[n] = *(const bf16x8*)&Bsm[h][wc * 64 + n * 16 + fr][fkx];

      #pragma unroll
      for (int m = 0; m < 4; ++m)
        #pragma unroll
        for (int n = 0; n < 4; ++n)
          acc[m][n] = __builtin_amdgcn_mfma_f32_16x16x32_bf16(af[m], bf[n], acc[m][n], 0, 0, 0);
    }
  }

  // epilogue: C/D layout col=lane&15, row=(lane>>4)*4+j (m89-verified)
  const int fq = lane >> 4;
  #pragma unroll
  for (int m = 0; m < 4; ++m) {
    #pragma unroll
    for (int n = 0; n < 4; ++n) {
      int col = n0 + wc * 64 + n * 16 + fr;
      int rowb = m0 + wr * 64 + m * 16 + fq * 4;
      #pragma unroll
      for (int j = 0; j < 4; ++j)
        C[(size_t)(rowb + j) * NCOLS + col] = f2b(acc[m][n][j]);
    }
  }
}

// ---------- kernel 4: windowed softmax + halves-sum + RMSNorm + RoPE + scatter ----------
__device__ inline float soft_half(const bf16x8* scv, const bf16x8* kvv,
                                  const float ap[4][8], const bool valid[4], int i) {
  float sc[4];
  #pragma unroll
  for (int r = 0; r < 4; ++r)
    sc[r] = valid[r] ? b2f((u16)scv[r][i]) : -1e30f;
  float m = fmaxf(fmaxf(sc[0], sc[1]), fmaxf(sc[2], sc[3]));
  float e[4], sum = 0.f;
  #pragma unroll
  for (int r = 0; r < 4; ++r) { e[r] = __expf(sc[r] - m); sum += e[r]; }
  float inv = 1.0f / sum;
  float o = 0.f;
  #pragma unroll
  for (int r = 0; r < 4; ++r)
    o += e[r] * (b2f((u16)kvv[r][i]) + ap[r][i]);
  return o * inv;
}

__global__ __launch_bounds__(256) void fuse_kernel(const u16* __restrict__ kvsc,
                                                   const float* __restrict__ ape,
                                                   const float* __restrict__ norm_w,
                                                   const float* __restrict__ cosb,
                                                   const float* __restrict__ sinb,
                                                   const int* __restrict__ bo,
                                                   float* __restrict__ ckv_out,
                                                   float* __restrict__ cache_out) {
  __shared__ float ape_s[4][1024];
  const int t = threadIdx.x;
  for (int j = t; j < 1024; j += 256)
    ((float4*)&ape_s[0][0])[j] = ((const float4*)ape)[j];
  __syncthreads();

  const int wave = t >> 6, lane = t & 63;
  const int g = blockIdx.x * 4 + wave;
  const int b = g >> 12, s = g & 4095;
  const int c0 = lane * 8;

  const u16* base = kvsc + (size_t)b * SLEN * NCOLS;
  bf16x8 kv_lo[4], kv_hi[4], sc_lo[4], sc_hi[4];
  float apl[4][8], aph[4][8];
  bool valid[4];
  #pragma unroll
  for (int r = 0; r < 4; ++r) {
    int sr = s - 3 + r;
    valid[r] = (sr >= 0);
    int src = sr < 0 ? 0 : sr;
    int rot = src & 3;
    const u16* rp = base + (size_t)src * NCOLS;
    kv_lo[r] = *(const bf16x8*)(rp + c0);
    kv_hi[r] = *(const bf16x8*)(rp + 512 + c0);
    sc_lo[r] = *(const bf16x8*)(rp + 1024 + c0);
    sc_hi[r] = *(const bf16x8*)(rp + 1536 + c0);
    *(float4*)&apl[r][0] = *(const float4*)&ape_s[rot][c0];
    *(float4*)&apl[r][4] = *(const float4*)&ape_s[rot][c0 + 4];
    *(float4*)&aph[r][0] = *(const float4*)&ape_s[rot][512 + c0];
    *(float4*)&aph[r][4] = *(const float4*)&ape_s[rot][512 + c0 + 4];
  }

  float res[8];
  float sumsq = 0.f;
  #pragma unroll
  for (int i = 0; i < 8; ++i) {
    float o = soft_half(sc_lo, kv_lo, apl, valid, i) +
              soft_half(sc_hi, kv_hi, aph, valid, i);
    res[i] = o;
    sumsq += o * o;
  }
  #pragma unroll
  for (int off = 32; off > 0; off >>= 1)
    sumsq += __shfl_xor(sumsq, off, 64);
  const float scale = rsqrtf(sumsq * (1.0f / 512.0f) + 1e-6f);

  float4 nwa = *(const float4*)&norm_w[c0];
  float4 nwb = *(const float4*)&norm_w[c0 + 4];
  res[0] *= scale * nwa.x; res[1] *= scale * nwa.y;
  res[2] *= scale * nwa.z; res[3] *= scale * nwa.w;
  res[4] *= scale * nwb.x; res[5] *= scale * nwb.y;
  res[6] *= scale * nwb.z; res[7] *= scale * nwb.w;

  if (lane >= 56) {   // channels 448..511: RoPE
    int j0 = (lane - 56) * 4;
    float4 cs = *(const float4*)&cosb[(size_t)s * 32 + j0];
    float4 sn = *(const float4*)&sinb[(size_t)s * 32 + j0];
    float cc[4] = {cs.x, cs.y, cs.z, cs.w};
    float ss[4] = {sn.x, sn.y, sn.z, sn.w};
    #pragma unroll
    for (int p = 0; p < 4; ++p) {
      float cr = res[2 * p], ci = res[2 * p + 1];
      res[2 * p]     = cr * cc[p] - ci * ss[p];
      res[2 * p + 1] = cr * ss[p] + ci * cc[p];
    }
  }

  float4 v0 = make_float4(res[0], res[1], res[2], res[3]);
  float4 v1 = make_float4(res[4], res[5], res[6], res[7]);
  float* op = ckv_out + (size_t)g * HD + c0;
  *(float4*)op = v0;
  *(float4*)(op + 4) = v1;

  if ((s & 3) == 3) {
    int cidx = s >> 2;
    int blk = bo[b * 16 + (cidx >> 6)];
    int off = cidx & 63;
    float* cp = cache_out + ((size_t)blk * 64 + off) * HD + c0;
    *(float4*)cp = v0;
    *(float4*)(cp + 4) = v1;
  }
}

// ---------- launch ----------
extern "C" void kernel_launch(void* const* d_in, const int* in_sizes, int n_in,
                              void* d_out, int out_size, void* d_ws, size_t ws_size,
                              hipStream_t stream) {
  const float* x    = (const float*)d_in[0];
  const float* wkv  = (const float*)d_in[1];
  const float* wg   = (const float*)d_in[2];
  const float* ape  = (const float*)d_in[3];
  const float* nw   = (const float*)d_in[4];
  const float* cosb = (const float*)d_in[5];
  const float* sinb = (const float*)d_in[6];
  const int*   bo   = (const int*)d_in[7];

  float* out = (float*)d_out;
  char* ws = (char*)d_ws;
  u16* xb   = (u16*)ws;                                              // 128 MiB
  u16* Wt   = (u16*)(ws + (size_t)MROWS * DIMK * 2);                 //  16 MiB
  u16* kvsc = (u16*)(ws + (size_t)MROWS * DIMK * 2 + (size_t)NCOLS * DIMK * 2); // 64 MiB

  hipLaunchKernelGGL(cvt_x_kernel, dim3(32768), dim3(256), 0, stream,
                     (const float4*)x, xb);
  hipLaunchKernelGGL(build_wt_kernel, dim3(32, 64), dim3(256), 0, stream, wkv, wg, Wt);
  hipLaunchKernelGGL(gemm_kernel, dim3(2048), dim3(256), 0, stream, xb, Wt, kvsc);

  float* ckv_out = out;
  float* cache_out = out + (size_t)MROWS * HD;
  hipMemsetAsync(cache_out, 0, (size_t)64 * 64 * HD * sizeof(float), stream);
  hipLaunchKernelGGL(fuse_kernel, dim3(MROWS / 4), dim3(256), 0, stream,
                     kvsc, ape, nw, cosb, sinb, bo, ckv_out, cache_out);
}

// Round 13
// 439.719 us; speedup vs baseline: 1.2856x; 1.2856x over previous
//
#include <hip/hip_runtime.h>

// Problem constants (match reference)
#define BATCH 4
#define SLEN  4096
#define DIMK  4096
#define HD    512
#define RD    64
#define NCOLS 2048          // [kv(1024) | sc(1024)]
#define MROWS (BATCH*SLEN)  // 16384

typedef __attribute__((ext_vector_type(8))) short bf16x8;
typedef __attribute__((ext_vector_type(4))) float f32x4;
typedef unsigned short u16;

// ---------- bf16 helpers ----------
__device__ inline u16 f2b(float f) {
  union { float f; unsigned u; } x; x.f = f;
  unsigned r = (x.u + 0x7fffu + ((x.u >> 16) & 1u)) >> 16;
  return (u16)r;
}
__device__ inline float b2f(u16 u) {
  union { float f; unsigned u; } x; x.u = ((unsigned)u) << 16; return x.f;
}

#define GLL16(gp, lp) __builtin_amdgcn_global_load_lds( \
    (__attribute__((address_space(1))) void*)(gp),      \
    (__attribute__((address_space(3))) void*)(lp), 16, 0, 0)

// ---------- kernel 1: x (f32) -> bf16 ----------
__global__ __launch_bounds__(256) void cvt_x_kernel(const float4* __restrict__ x,
                                                    u16* __restrict__ xb) {
  size_t i = (size_t)blockIdx.x * 256 + threadIdx.x;
  float4 a = x[2 * i], b = x[2 * i + 1];
  bf16x8 v;
  v[0] = (short)f2b(a.x); v[1] = (short)f2b(a.y);
  v[2] = (short)f2b(a.z); v[3] = (short)f2b(a.w);
  v[4] = (short)f2b(b.x); v[5] = (short)f2b(b.y);
  v[6] = (short)f2b(b.z); v[7] = (short)f2b(b.w);
  *(bf16x8*)(xb + i * 8) = v;
}

// ---------- kernel 2: Wt[n][k] = [wkv|wgate][k][n] as bf16 ----------
__global__ __launch_bounds__(256) void build_wt_kernel(const float* __restrict__ wkv,
                                                       const float* __restrict__ wg,
                                                       u16* __restrict__ Wt) {
  __shared__ u16 tile[64][72];
  const int n0 = blockIdx.x * 64;
  const int k0 = blockIdx.y * 64;
  const float* src = (n0 < 1024) ? wkv : wg;
  const int nbase = (n0 < 1024) ? n0 : (n0 - 1024);
  const int t = threadIdx.x;
  const int nn = t & 63, kq = t >> 6;
  #pragma unroll
  for (int j = 0; j < 16; ++j) {
    int k = kq + j * 4;
    float v = src[(size_t)(k0 + k) * 1024 + nbase + nn];
    tile[nn][k] = f2b(v);
  }
  __syncthreads();
  const int kk8 = (t & 7) * 8;
  #pragma unroll
  for (int j = 0; j < 2; ++j) {
    int nn2 = (t >> 3) + j * 32;
    bf16x8 v = *(bf16x8*)&tile[nn2][kk8];
    *(bf16x8*)&Wt[(size_t)(n0 + nn2) * DIMK + k0 + kk8] = v;
  }
}

// ---------- kernel 3: GEMM — m97 structure, BK=32 (R11 WIN config) ----------
// R12 lesson: BK=64 single-buffered regressed (exposed 8-GLL burst tail).
// R11 = session best: 727 TF. This round's single variable: block->tile
// mapping. R11's column-banding streamed ALL of A per XCD (FETCH 1.17 GB
// HBM @3.4 TB/s). nt-fast chunked mapping (R2-R10, FETCH ~197 MB measured)
// shares A panels among the 16 nt-neighbors inside each XCD chunk -> L2/L3
// serve A re-reads, HBM pressure drops 5x.
__global__ __launch_bounds__(256, 4) void gemm_kernel(const u16* __restrict__ A,
                                                      const u16* __restrict__ Bt,
                                                      u16* __restrict__ C) {
  __shared__ __align__(16) u16 Asm[128][32];        // 8 KiB
  __shared__ __align__(16) u16 Bsm[128][32];        // 8 KiB
  const int t = threadIdx.x;
  const int lane = t & 63, wave = t >> 6;

  // nt-fast chunked XCD swizzle: nwg=2048, 256 contiguous lids per XCD;
  // lid -> (mt = lid>>4, nt = lid&15): 16 nt-neighbors share each A panel.
  const int orig = blockIdx.x;
  const int lid = (orig & 7) * 256 + (orig >> 3);
  const int mt = lid >> 4, nt = lid & 15;
  const int m0 = mt * 128, n0 = nt * 128;
  const int wr = wave >> 1, wc = wave & 1;          // 2x2 waves of 64x64

  f32x4 acc[4][4] = {};

  // staging map: thread t -> rowT = t>>2 (0..63), granule colT = t&3 (16B).
  // LDS linear offset = t*16 per GLL. global granule pre-swizzled:
  // colX = colT ^ X(rowT), X(r) = (r&3)^((r>>2)&3); X(r+64) = X(r).
  const int rowT = t >> 2, colT = t & 3;
  const int colX = colT ^ (rowT & 3) ^ ((rowT >> 2) & 3);
  const u16* gA0 = A  + (size_t)(m0 + rowT) * DIMK + colX * 8;
  const u16* gB0 = Bt + (size_t)(n0 + rowT) * DIMK + colX * 8;
  const u16* gA1 = A  + (size_t)(m0 + 64 + rowT) * DIMK + colX * 8;
  const u16* gB1 = Bt + (size_t)(n0 + 64 + rowT) * DIMK + colX * 8;
  u16* lA0 = &Asm[rowT][colT * 8];
  u16* lA1 = &Asm[64 + rowT][colT * 8];
  u16* lB0 = &Bsm[rowT][colT * 8];
  u16* lB1 = &Bsm[64 + rowT][colT * 8];

  // fragment read addressing (swizzled k-granule; X depends only on fr)
  const int fr = lane & 15, fk = lane >> 4;
  const int fkx = (fk ^ (fr & 3) ^ ((fr >> 2) & 3)) * 8;

  for (int kk = 0; kk < DIMK; kk += 32) {
    __syncthreads();                 // previous step's LDS reads complete
    GLL16(gA0 + kk, lA0);
    GLL16(gA1 + kk, lA1);
    GLL16(gB0 + kk, lB0);
    GLL16(gB1 + kk, lB1);
    __syncthreads();                 // loads landed (compiler drains vmcnt)

    bf16x8 af[4], bf[4];
    #pragma unroll
    for (int m = 0; m < 4; ++m)
      af[m] = *(const bf16x8*)&Asm[wr * 64 + m * 16 + fr][fkx];
    #pragma unroll
    for (int n = 0; n < 4; ++n)
      bf[n] = *(const bf16x8*)&Bsm[wc * 64 + n * 16 + fr][fkx];

    #pragma unroll
    for (int m = 0; m < 4; ++m)
      #pragma unroll
      for (int n = 0; n < 4; ++n)
        acc[m][n] = __builtin_amdgcn_mfma_f32_16x16x32_bf16(af[m], bf[n], acc[m][n], 0, 0, 0);
  }

  // epilogue: C/D layout col=lane&15, row=(lane>>4)*4+j (m89-verified)
  const int fq = lane >> 4;
  #pragma unroll
  for (int m = 0; m < 4; ++m) {
    #pragma unroll
    for (int n = 0; n < 4; ++n) {
      int col = n0 + wc * 64 + n * 16 + fr;
      int rowb = m0 + wr * 64 + m * 16 + fq * 4;
      #pragma unroll
      for (int j = 0; j < 4; ++j)
        C[(size_t)(rowb + j) * NCOLS + col] = f2b(acc[m][n][j]);
    }
  }
}

// ---------- kernel 4: windowed softmax + halves-sum + RMSNorm + RoPE + scatter ----------
__device__ inline float soft_half(const bf16x8* scv, const bf16x8* kvv,
                                  const float ap[4][8], const bool valid[4], int i) {
  float sc[4];
  #pragma unroll
  for (int r = 0; r < 4; ++r)
    sc[r] = valid[r] ? b2f((u16)scv[r][i]) : -1e30f;
  float m = fmaxf(fmaxf(sc[0], sc[1]), fmaxf(sc[2], sc[3]));
  float e[4], sum = 0.f;
  #pragma unroll
  for (int r = 0; r < 4; ++r) { e[r] = __expf(sc[r] - m); sum += e[r]; }
  float inv = 1.0f / sum;
  float o = 0.f;
  #pragma unroll
  for (int r = 0; r < 4; ++r)
    o += e[r] * (b2f((u16)kvv[r][i]) + ap[r][i]);
  return o * inv;
}

__global__ __launch_bounds__(256) void fuse_kernel(const u16* __restrict__ kvsc,
                                                   const float* __restrict__ ape,
                                                   const float* __restrict__ norm_w,
                                                   const float* __restrict__ cosb,
                                                   const float* __restrict__ sinb,
                                                   const int* __restrict__ bo,
                                                   float* __restrict__ ckv_out,
                                                   float* __restrict__ cache_out) {
  __shared__ float ape_s[4][1024];
  const int t = threadIdx.x;
  for (int j = t; j < 1024; j += 256)
    ((float4*)&ape_s[0][0])[j] = ((const float4*)ape)[j];
  __syncthreads();

  const int wave = t >> 6, lane = t & 63;
  const int g = blockIdx.x * 4 + wave;
  const int b = g >> 12, s = g & 4095;
  const int c0 = lane * 8;

  const u16* base = kvsc + (size_t)b * SLEN * NCOLS;
  bf16x8 kv_lo[4], kv_hi[4], sc_lo[4], sc_hi[4];
  float apl[4][8], aph[4][8];
  bool valid[4];
  #pragma unroll
  for (int r = 0; r < 4; ++r) {
    int sr = s - 3 + r;
    valid[r] = (sr >= 0);
    int src = sr < 0 ? 0 : sr;
    int rot = src & 3;
    const u16* rp = base + (size_t)src * NCOLS;
    kv_lo[r] = *(const bf16x8*)(rp + c0);
    kv_hi[r] = *(const bf16x8*)(rp + 512 + c0);
    sc_lo[r] = *(const bf16x8*)(rp + 1024 + c0);
    sc_hi[r] = *(const bf16x8*)(rp + 1536 + c0);
    *(float4*)&apl[r][0] = *(const float4*)&ape_s[rot][c0];
    *(float4*)&apl[r][4] = *(const float4*)&ape_s[rot][c0 + 4];
    *(float4*)&aph[r][0] = *(const float4*)&ape_s[rot][512 + c0];
    *(float4*)&aph[r][4] = *(const float4*)&ape_s[rot][512 + c0 + 4];
  }

  float res[8];
  float sumsq = 0.f;
  #pragma unroll
  for (int i = 0; i < 8; ++i) {
    float o = soft_half(sc_lo, kv_lo, apl, valid, i) +
              soft_half(sc_hi, kv_hi, aph, valid, i);
    res[i] = o;
    sumsq += o * o;
  }
  #pragma unroll
  for (int off = 32; off > 0; off >>= 1)
    sumsq += __shfl_xor(sumsq, off, 64);
  const float scale = rsqrtf(sumsq * (1.0f / 512.0f) + 1e-6f);

  float4 nwa = *(const float4*)&norm_w[c0];
  float4 nwb = *(const float4*)&norm_w[c0 + 4];
  res[0] *= scale * nwa.x; res[1] *= scale * nwa.y;
  res[2] *= scale * nwa.z; res[3] *= scale * nwa.w;
  res[4] *= scale * nwb.x; res[5] *= scale * nwb.y;
  res[6] *= scale * nwb.z; res[7] *= scale * nwb.w;

  if (lane >= 56) {   // channels 448..511: RoPE
    int j0 = (lane - 56) * 4;
    float4 cs = *(const float4*)&cosb[(size_t)s * 32 + j0];
    float4 sn = *(const float4*)&sinb[(size_t)s * 32 + j0];
    float cc[4] = {cs.x, cs.y, cs.z, cs.w};
    float ss[4] = {sn.x, sn.y, sn.z, sn.w};
    #pragma unroll
    for (int p = 0; p < 4; ++p) {
      float cr = res[2 * p], ci = res[2 * p + 1];
      res[2 * p]     = cr * cc[p] - ci * ss[p];
      res[2 * p + 1] = cr * ss[p] + ci * cc[p];
    }
  }

  float4 v0 = make_float4(res[0], res[1], res[2], res[3]);
  float4 v1 = make_float4(res[4], res[5], res[6], res[7]);
  float* op = ckv_out + (size_t)g * HD + c0;
  *(float4*)op = v0;
  *(float4*)(op + 4) = v1;

  if ((s & 3) == 3) {
    int cidx = s >> 2;
    int blk = bo[b * 16 + (cidx >> 6)];
    int off = cidx & 63;
    float* cp = cache_out + ((size_t)blk * 64 + off) * HD + c0;
    *(float4*)cp = v0;
    *(float4*)(cp + 4) = v1;
  }
}

// ---------- launch ----------
extern "C" void kernel_launch(void* const* d_in, const int* in_sizes, int n_in,
                              void* d_out, int out_size, void* d_ws, size_t ws_size,
                              hipStream_t stream) {
  const float* x    = (const float*)d_in[0];
  const float* wkv  = (const float*)d_in[1];
  const float* wg   = (const float*)d_in[2];
  const float* ape  = (const float*)d_in[3];
  const float* nw   = (const float*)d_in[4];
  const float* cosb = (const float*)d_in[5];
  const float* sinb = (const float*)d_in[6];
  const int*   bo   = (const int*)d_in[7];

  float* out = (float*)d_out;
  char* ws = (char*)d_ws;
  u16* xb   = (u16*)ws;                                              // 128 MiB
  u16* Wt   = (u16*)(ws + (size_t)MROWS * DIMK * 2);                 //  16 MiB
  u16* kvsc = (u16*)(ws + (size_t)MROWS * DIMK * 2 + (size_t)NCOLS * DIMK * 2); // 64 MiB

  hipLaunchKernelGGL(cvt_x_kernel, dim3(32768), dim3(256), 0, stream,
                     (const float4*)x, xb);
  hipLaunchKernelGGL(build_wt_kernel, dim3(32, 64), dim3(256), 0, stream, wkv, wg, Wt);
  hipLaunchKernelGGL(gemm_kernel, dim3(2048), dim3(256), 0, stream, xb, Wt, kvsc);

  float* ckv_out = out;
  float* cache_out = out + (size_t)MROWS * HD;
  hipMemsetAsync(cache_out, 0, (size_t)64 * 64 * HD * sizeof(float), stream);
  hipLaunchKernelGGL(fuse_kernel, dim3(MROWS / 4), dim3(256), 0, stream,
                     kvsc, ape, nw, cosb, sinb, bo, ckv_out, cache_out);
}